// Round 2
// baseline (163.402 us; speedup 1.0000x reference)
//
#include <hip/hip_runtime.h>

// TotalDegree: out[b, t] = prod over multiset term t of x[b, d]; terms = all
// multisets of size 0..4 over 8 vars, DFS-lexicographic order (495 terms).
// Factorization (verified in prior rounds): term = P[u]*P[v], P = 45 multisets
// of size <= 2. R3 redesign: P table staged in LDS per wave (4 rows x 64 slots),
// gathers are plain ds_read_b32 (replaces ds_bpermute, suspected ~4x slower),
// and output is written per 4-row group: 4*495 = 1980 floats = 7920 B, which is
// 16-B aligned -> dense global_store_dwordx4 nontemporal stores (2/row vs 8/row
// dword), no per-row ragged tail. Element routing is a compile-time table:
// 8 chunks x 4 elems per lane, packed (row*64+u | (row*64+v)<<8) as u16.
// R4: fix compile error -- __builtin_nontemporal_store needs a clang ext_vector
// type, not HIP's float4 class.

typedef float f32x4 __attribute__((ext_vector_type(4)));

struct Tbl {
    unsigned short e[64][8][4];  // [lane][chunk][k]: LDS word idx of u | v<<8
    unsigned short pp[64];       // per lane: s1 | s2<<4 | use1<<8 | use2<<9
};

constexpr int pidx_c(int a, int b) {
    return 9 + 8 * a - (a * (a - 1)) / 2 + (b - a);  // empty=0, singles 1..8, pairs 9..44
}

constexpr Tbl make_tbl() {
    Tbl T{};
    // DFS preorder over non-decreasing tuples == reference's sorted order.
    unsigned short lin[512] = {};  // t -> u | v<<8 ; t=0 and t>=495 -> P0*P0 = 1
    int idx = 1;
    for (int a = 0; a < 8; ++a) {
        lin[idx++] = (unsigned short)(1 + a);
        for (int b = a; b < 8; ++b) {
            lin[idx++] = (unsigned short)pidx_c(a, b);
            for (int c = b; c < 8; ++c) {
                lin[idx++] = (unsigned short)(pidx_c(a, b) | ((1 + c) << 8));
                for (int d = c; d < 8; ++d)
                    lin[idx++] = (unsigned short)(pidx_c(a, b) | (pidx_c(c, d) << 8));
            }
        }
    }  // idx == 495
    // Flat element ei = c*256 + 4*lane + k over a 4-row group (4*495 = 1980).
    for (int l = 0; l < 64; ++l)
        for (int c = 0; c < 8; ++c)
            for (int k = 0; k < 4; ++k) {
                int ei = c * 256 + 4 * l + k;
                if (ei < 1980) {
                    int r = ei / 495, t = ei % 495;
                    int u = lin[t] & 255, v = lin[t] >> 8;
                    T.e[l][c][k] = (unsigned short)((r * 64 + u) | ((r * 64 + v) << 8));
                } else {
                    T.e[l][c][k] = 0;  // masked-off lanes of chunk 7 read P[0]=1
                }
            }
    for (int l = 0; l < 64; ++l) {
        int s1 = 0, s2 = 0, u1 = 0, u2 = 0;
        if (l >= 1 && l <= 8) { s1 = l - 1; u1 = 1; }
        else if (l >= 9 && l < 45) {
            int k = l - 9, i = 0;
            while (k >= 8 - i) { k -= 8 - i; ++i; }
            s1 = i; s2 = i + k; u1 = 1; u2 = 1;
        }
        T.pp[l] = (unsigned short)(s1 | (s2 << 4) | (u1 << 8) | (u2 << 9));
    }
    return T;
}

__constant__ Tbl TBL = make_tbl();

#define WAVES_PER_BLOCK 4
#define ROWS_PER_WAVE   8
#define ROWS_PER_BLOCK  (WAVES_PER_BLOCK * ROWS_PER_WAVE)  // 32

__global__ __launch_bounds__(256, 8) void TotalDegree_29755533426739_kernel(
    const float* __restrict__ x, float* __restrict__ out, int B) {
    __shared__ float xs[ROWS_PER_BLOCK * 8];       // 1 KB x-tile
    __shared__ float Pl[WAVES_PER_BLOCK][256];     // per-wave P table, 4 rows x 64

    const int tid  = (int)threadIdx.x;
    const int lane = tid & 63;
    const int wid  = tid >> 6;

    // Bulk coalesced x-tile load: 256 threads x 4 B = 32 rows.
    {
        const int gi = (int)blockIdx.x * (ROWS_PER_BLOCK * 8) + tid;
        xs[tid] = (gi < B * 8) ? x[gi] : 0.0f;
    }

    // Per-lane row-invariant constants.
    const int ppv  = (int)TBL.pp[lane];
    const int s1   = ppv & 15;
    const int s2   = (ppv >> 4) & 15;
    const bool use1 = ((ppv >> 8) & 1) != 0;
    const bool use2 = ((ppv >> 9) & 1) != 0;

    // Element-routing table: 8 B per chunk, contiguous 64 B per lane -> 16 VGPRs.
    unsigned long long tw[8];
    #pragma unroll
    for (int c = 0; c < 8; ++c)
        tw[c] = *reinterpret_cast<const unsigned long long*>(&TBL.e[lane][c][0]);

    __syncthreads();

    const float* xw = xs + wid * (ROWS_PER_WAVE * 8);  // this wave's 8 rows
    float* Pw = Pl[wid];
    const unsigned rowBase =
        (unsigned)blockIdx.x * ROWS_PER_BLOCK + (unsigned)(wid * ROWS_PER_WAVE);

    #pragma unroll
    for (int g = 0; g < 2; ++g) {  // two 4-row groups per wave
        // Build P table for 4 rows. Lanes 45..63 write garbage*1.0 into unused
        // slots (stride 64 keeps them inside this row's region; gathers never
        // hit them). Same-wave LDS is in-order; Pw is wave-private: no barrier.
        #pragma unroll
        for (int r = 0; r < 4; ++r) {
            const float a1 = xw[(g * 4 + r) * 8 + s1];  // 8-word window, bcast reads
            const float a2 = xw[(g * 4 + r) * 8 + s2];
            Pw[r * 64 + lane] = (use1 ? a1 : 1.0f) * (use2 ? a2 : 1.0f);
        }

        // 4-row group output: base row % 4 == 0 -> byte base % 16 == 0.
        float* o = out + (rowBase + (unsigned)(g * 4)) * 495u;
        f32x4* ob = reinterpret_cast<f32x4*>(o) + lane;

        #pragma unroll
        for (int c = 0; c < 8; ++c) {
            const unsigned w0 = (unsigned)tw[c];
            const unsigned w1 = (unsigned)(tw[c] >> 32);
            f32x4 v;
            v.x = Pw[w0 & 255] * Pw[(w0 >> 8) & 255];
            v.y = Pw[(w0 >> 16) & 255] * Pw[w0 >> 24];
            v.z = Pw[w1 & 255] * Pw[(w1 >> 8) & 255];
            v.w = Pw[(w1 >> 16) & 255] * Pw[w1 >> 24];
            if (c < 7) {
                // imm offsets 0..6144 B off one addr reg; 1 KB per wave-store
                __builtin_nontemporal_store(v, ob + c * 64);
            } else if (lane < 47) {  // tail: elements 1792..1979 = 47 x4 exactly
                __builtin_nontemporal_store(v, ob + 448);
            }
        }
    }
}

extern "C" void kernel_launch(void* const* d_in, const int* in_sizes, int n_in,
                              void* d_out, int out_size, void* d_ws, size_t ws_size,
                              hipStream_t stream) {
    const float* x = (const float*)d_in[0];
    float* out = (float*)d_out;
    const int B = in_sizes[0] / 8;  // 65536 rows
    const int grid = (B + ROWS_PER_BLOCK - 1) / ROWS_PER_BLOCK;  // 2048
    hipLaunchKernelGGL(TotalDegree_29755533426739_kernel,
                       dim3(grid), dim3(256), 0, stream, x, out, B);
}

// Round 3
// 145.829 us; speedup vs baseline: 1.1205x; 1.1205x over previous
//
#include <hip/hip_runtime.h>

// TotalDegree: out[b, t] = prod over multiset term t of x[b, d]; terms = all
// multisets of size 0..4 over 8 vars, DFS-lexicographic order (495 terms).
// Factorization (verified): term = P[u]*P[v], P = 45 multisets of size <= 2.
// Structure (R4): P table in LDS per wave (4 rows x 64 slots), gathers are
// plain ds_read_b32 (<=4-way conflicts on 3/8 chunks, rest 2-way = free), and
// output written per 4-row group: 4*495 = 1980 floats = 495 f32x4, 16-B
// aligned -> dense global_store_dwordx4 (2/row vs 8/row dword), no ragged
// per-row tail. Routing is a compile-time table: 8 chunks x 4 elems per lane,
// packed (row*64+u | (row*64+v)<<8) as u16.
// R5: SINGLE-VARIABLE CHANGE vs R4 -- drop the nontemporal flag (plain vector
// stores). Theory: nt defeated TCC write-combining on this write-only stream
// (R4 regressed +16 us clock-normalized with identical instruction mix
// otherwise); NT was the only categorical diff vs the 130.5-us baseline path.

typedef float f32x4 __attribute__((ext_vector_type(4)));

struct Tbl {
    unsigned short e[64][8][4];  // [lane][chunk][k]: LDS word idx of u | v<<8
    unsigned short pp[64];       // per lane: s1 | s2<<4 | use1<<8 | use2<<9
};

constexpr int pidx_c(int a, int b) {
    return 9 + 8 * a - (a * (a - 1)) / 2 + (b - a);  // empty=0, singles 1..8, pairs 9..44
}

constexpr Tbl make_tbl() {
    Tbl T{};
    // DFS preorder over non-decreasing tuples == reference's sorted order.
    unsigned short lin[512] = {};  // t -> u | v<<8 ; t=0 and t>=495 -> P0*P0 = 1
    int idx = 1;
    for (int a = 0; a < 8; ++a) {
        lin[idx++] = (unsigned short)(1 + a);
        for (int b = a; b < 8; ++b) {
            lin[idx++] = (unsigned short)pidx_c(a, b);
            for (int c = b; c < 8; ++c) {
                lin[idx++] = (unsigned short)(pidx_c(a, b) | ((1 + c) << 8));
                for (int d = c; d < 8; ++d)
                    lin[idx++] = (unsigned short)(pidx_c(a, b) | (pidx_c(c, d) << 8));
            }
        }
    }  // idx == 495
    // Flat element ei = c*256 + 4*lane + k over a 4-row group (4*495 = 1980).
    for (int l = 0; l < 64; ++l)
        for (int c = 0; c < 8; ++c)
            for (int k = 0; k < 4; ++k) {
                int ei = c * 256 + 4 * l + k;
                if (ei < 1980) {
                    int r = ei / 495, t = ei % 495;
                    int u = lin[t] & 255, v = lin[t] >> 8;
                    T.e[l][c][k] = (unsigned short)((r * 64 + u) | ((r * 64 + v) << 8));
                } else {
                    T.e[l][c][k] = 0;  // masked-off lanes of chunk 7 read P[0]=1
                }
            }
    for (int l = 0; l < 64; ++l) {
        int s1 = 0, s2 = 0, u1 = 0, u2 = 0;
        if (l >= 1 && l <= 8) { s1 = l - 1; u1 = 1; }
        else if (l >= 9 && l < 45) {
            int k = l - 9, i = 0;
            while (k >= 8 - i) { k -= 8 - i; ++i; }
            s1 = i; s2 = i + k; u1 = 1; u2 = 1;
        }
        T.pp[l] = (unsigned short)(s1 | (s2 << 4) | (u1 << 8) | (u2 << 9));
    }
    return T;
}

__constant__ Tbl TBL = make_tbl();

#define WAVES_PER_BLOCK 4
#define ROWS_PER_WAVE   8
#define ROWS_PER_BLOCK  (WAVES_PER_BLOCK * ROWS_PER_WAVE)  // 32

__global__ __launch_bounds__(256, 8) void TotalDegree_29755533426739_kernel(
    const float* __restrict__ x, float* __restrict__ out, int B) {
    __shared__ float xs[ROWS_PER_BLOCK * 8];       // 1 KB x-tile
    __shared__ float Pl[WAVES_PER_BLOCK][256];     // per-wave P table, 4 rows x 64

    const int tid  = (int)threadIdx.x;
    const int lane = tid & 63;
    const int wid  = tid >> 6;

    // Bulk coalesced x-tile load: 256 threads x 4 B = 32 rows.
    {
        const int gi = (int)blockIdx.x * (ROWS_PER_BLOCK * 8) + tid;
        xs[tid] = (gi < B * 8) ? x[gi] : 0.0f;
    }

    // Per-lane row-invariant constants.
    const int ppv  = (int)TBL.pp[lane];
    const int s1   = ppv & 15;
    const int s2   = (ppv >> 4) & 15;
    const bool use1 = ((ppv >> 8) & 1) != 0;
    const bool use2 = ((ppv >> 9) & 1) != 0;

    // Element-routing table: 8 B per chunk, contiguous 64 B per lane -> 16 VGPRs.
    unsigned long long tw[8];
    #pragma unroll
    for (int c = 0; c < 8; ++c)
        tw[c] = *reinterpret_cast<const unsigned long long*>(&TBL.e[lane][c][0]);

    __syncthreads();

    const float* xw = xs + wid * (ROWS_PER_WAVE * 8);  // this wave's 8 rows
    float* Pw = Pl[wid];
    const unsigned rowBase =
        (unsigned)blockIdx.x * ROWS_PER_BLOCK + (unsigned)(wid * ROWS_PER_WAVE);

    #pragma unroll
    for (int g = 0; g < 2; ++g) {  // two 4-row groups per wave
        // Build P table for 4 rows. Lanes 45..63 write garbage*1.0 into unused
        // slots (stride 64 keeps them inside this row's region; gathers never
        // hit them). Same-wave LDS ops execute in order; Pw is wave-private:
        // no barrier needed.
        #pragma unroll
        for (int r = 0; r < 4; ++r) {
            const float a1 = xw[(g * 4 + r) * 8 + s1];  // 8-word window, bcast reads
            const float a2 = xw[(g * 4 + r) * 8 + s2];
            Pw[r * 64 + lane] = (use1 ? a1 : 1.0f) * (use2 ? a2 : 1.0f);
        }

        // 4-row group output: base row % 4 == 0 -> byte base % 16 == 0.
        float* o = out + (rowBase + (unsigned)(g * 4)) * 495u;
        f32x4* ob = reinterpret_cast<f32x4*>(o) + lane;

        #pragma unroll
        for (int c = 0; c < 8; ++c) {
            const unsigned w0 = (unsigned)tw[c];
            const unsigned w1 = (unsigned)(tw[c] >> 32);
            f32x4 v;
            v.x = Pw[w0 & 255] * Pw[(w0 >> 8) & 255];
            v.y = Pw[(w0 >> 16) & 255] * Pw[w0 >> 24];
            v.z = Pw[w1 & 255] * Pw[(w1 >> 8) & 255];
            v.w = Pw[(w1 >> 16) & 255] * Pw[w1 >> 24];
            if (c < 7) {
                ob[c * 64] = v;          // imm offsets off one addr reg, 1 KB/wave-store
            } else if (lane < 47) {      // tail: elements 1792..1979 = 47 x4 exactly
                ob[448] = v;
            }
        }
    }
}

extern "C" void kernel_launch(void* const* d_in, const int* in_sizes, int n_in,
                              void* d_out, int out_size, void* d_ws, size_t ws_size,
                              hipStream_t stream) {
    const float* x = (const float*)d_in[0];
    float* out = (float*)d_out;
    const int B = in_sizes[0] / 8;  // 65536 rows
    const int grid = (B + ROWS_PER_BLOCK - 1) / ROWS_PER_BLOCK;  // 2048
    hipLaunchKernelGGL(TotalDegree_29755533426739_kernel,
                       dim3(grid), dim3(256), 0, stream, x, out, B);
}

// Round 4
// 129.786 us; speedup vs baseline: 1.2590x; 1.1236x over previous
//
#include <hip/hip_runtime.h>

// TotalDegree: out[b, t] = prod over multiset term t of x[b, d]; 495 terms =
// multisets of size 0..4 over 8 vars, DFS-lex order. term = P[u]*P[v], P = 45
// multisets of size <= 2 (verified factorization).
// R6 EXPERIMENT (single concept): line-aligned flat store tiling. R2 (bpermute)
// and R5 (LDS gather) tied at ~52 us vs 21 us write floor -> shared bottleneck
// is the store stream. Both stored at 4-row-group granularity (7920-B stride,
// 16-B aligned only) -> every store instr partially covers its head/tail 128-B
// line. Theory: TCC read-allocates on partial-line store miss -> hidden ~124 MB
// fetch. Fix: tile each block's 63360-B span (= exactly 495 lines) into 62 flat
// 1-KB units; every global_store_dwordx4 covers 8 (tail: 7) FULL lines. Values
// unchanged: P staged in LDS for all 32 block rows; per-lane (row, term) tracked
// incrementally; term->(u,v) from a 4-way-interleaved LDS table (lanes' t
// stride-4 -> interleave makes the 4 uv reads conflict-free).

typedef float f32x4 __attribute__((ext_vector_type(4)));

struct Tbl {
    unsigned uv4[512];       // [(t&3)*128 + (t>>2)] = u | v<<16, t in 0..498
    unsigned short pp[64];   // per lane: s1 | s2<<4 | use1<<8 | use2<<9
};

constexpr int pidx_c(int a, int b) {
    return 9 + 8 * a - (a * (a - 1)) / 2 + (b - a);  // empty=0, singles 1..8, pairs 9..44
}

constexpr Tbl make_tbl() {
    Tbl T{};
    unsigned lin[500] = {};
    int idx = 1;  // term 0 = empty -> u=v=0 -> P[0]*P[0] = 1
    for (int a = 0; a < 8; ++a) {
        lin[idx++] = (unsigned)(1 + a);
        for (int b = a; b < 8; ++b) {
            lin[idx++] = (unsigned)pidx_c(a, b);
            for (int c = b; c < 8; ++c) {
                lin[idx++] = (unsigned)pidx_c(a, b) | ((unsigned)(1 + c) << 16);
                for (int d = c; d < 8; ++d)
                    lin[idx++] = (unsigned)pidx_c(a, b) | ((unsigned)pidx_c(c, d) << 16);
            }
        }
    }  // idx == 495; pad so reads at t..t+3 (t<=494) stay valid, wrapped rows
    for (int i = 0; i < 5; ++i) lin[495 + i] = lin[i];
    for (int t = 0; t < 499; ++t) T.uv4[(t & 3) * 128 + (t >> 2)] = lin[t];
    for (int l = 0; l < 64; ++l) {
        int s1 = 0, s2 = 0, u1 = 0, u2 = 0;
        if (l >= 1 && l <= 8) { s1 = l - 1; u1 = 1; }
        else if (l >= 9 && l < 45) {
            int k = l - 9, i = 0;
            while (k >= 8 - i) { k -= 8 - i; ++i; }
            s1 = i; s2 = i + k; u1 = 1; u2 = 1;
        }
        T.pp[l] = (unsigned short)(s1 | (s2 << 4) | (u1 << 8) | (u2 << 9));
    }
    return T;
}

__constant__ Tbl TBL = make_tbl();

#define ROWS_PER_BLOCK 32
#define WORDS_PER_BLOCK (ROWS_PER_BLOCK * 495)  // 15840 words = 63360 B = 495 lines
#define UNITS 62                                // 61 full 1-KB units + 896-B tail

__global__ __launch_bounds__(256, 8) void TotalDegree_29755533426739_kernel(
    const float* __restrict__ x, float* __restrict__ out, int B) {
    __shared__ float xs[256];                    // 32-row x tile
    __shared__ float P[ROWS_PER_BLOCK * 64];     // 8 KB: P[row][0..44] (45..63 junk)
    __shared__ unsigned uvt[512];                // interleaved term->uv map

    const int tid  = (int)threadIdx.x;
    const int lane = tid & 63;
    const int wid  = tid >> 6;

    // Coalesced x-tile load: 256 threads x 4 B = 32 rows.
    {
        const int gi = (int)blockIdx.x * 256 + tid;
        xs[tid] = (gi < B * 8) ? x[gi] : 0.0f;
    }

    // P build: wave w builds rows w*8..w*8+7, reading only its own wave's xs
    // segment (written by the same wave -> no barrier needed before this).
    const int ppv  = (int)TBL.pp[lane];
    const int s1   = ppv & 15;
    const int s2   = (ppv >> 4) & 15;
    const bool use1 = ((ppv >> 8) & 1) != 0;
    const bool use2 = ((ppv >> 9) & 1) != 0;
    const float* xw = xs + wid * 64;
    #pragma unroll
    for (int rr = 0; rr < 8; ++rr) {
        const float a1 = xw[rr * 8 + s1];
        const float a2 = xw[rr * 8 + s2];
        P[(wid * 8 + rr) * 64 + lane] = (use1 ? a1 : 1.0f) * (use2 ? a2 : 1.0f);
    }
    // uv table -> LDS (2 entries per thread).
    if (tid < 256) {
        uvt[tid] = TBL.uv4[tid];
        uvt[tid + 256] = TBL.uv4[tid + 256];
    }
    __syncthreads();  // cross-wave P reads below

    // Flat tiling: unit s covers words [s*256, s*256+256) of the block span.
    // Lane owns words f..f+3, f = s*256 + 4*lane; row r = f/495, term t = f%495.
    float* oB = out + (unsigned)blockIdx.x * WORDS_PER_BLOCK;
    {
        const int f0 = wid * 256 + (lane << 2);  // <= 1020
        int r0 = (f0 >= 990) ? 2 : (f0 >= 495 ? 1 : 0);
        int t  = f0 - r0 * 495;
        int rb = r0 << 6;  // r*64: word offset of row r's P slice

        for (int s = wid; s < UNITS; s += 4) {
            // term->uv for t..t+3 (interleaved layout: conflict-free across lanes)
            const unsigned q0 = uvt[((t    ) & 3) * 128 + ((t    ) >> 2)];
            const unsigned q1 = uvt[((t + 1) & 3) * 128 + ((t + 1) >> 2)];
            const unsigned q2 = uvt[((t + 2) & 3) * 128 + ((t + 2) >> 2)];
            const unsigned q3 = uvt[((t + 3) & 3) * 128 + ((t + 3) >> 2)];
            // elements past a row boundary (t+k >= 495) belong to row r+1
            const int w1 = (t >= 494) ? 64 : 0;
            const int w2 = (t >= 493) ? 64 : 0;
            const int w3 = (t >= 492) ? 64 : 0;
            f32x4 v;
            v.x = P[rb      + (int)(q0 & 0xffffu)] * P[rb      + (int)(q0 >> 16)];
            v.y = P[rb + w1 + (int)(q1 & 0xffffu)] * P[rb + w1 + (int)(q1 >> 16)];
            v.z = P[rb + w2 + (int)(q2 & 0xffffu)] * P[rb + w2 + (int)(q2 >> 16)];
            v.w = P[rb + w3 + (int)(q3 & 0xffffu)] * P[rb + w3 + (int)(q3 >> 16)];
            // unit base byte = blk*63360 + s*1024: both line-multiples -> every
            // store covers whole 128-B lines. Tail unit: 224 words = 56 lanes.
            if (s < UNITS - 1 || lane < 56)
                *reinterpret_cast<f32x4*>(oB + s * 256 + (lane << 2)) = v;
            // advance 4 units = 1024 words = 2*495 + 34
            t += 34; rb += 128;
            if (t >= 495) { t -= 495; rb += 64; }
        }
    }
}

extern "C" void kernel_launch(void* const* d_in, const int* in_sizes, int n_in,
                              void* d_out, int out_size, void* d_ws, size_t ws_size,
                              hipStream_t stream) {
    const float* x = (const float*)d_in[0];
    float* out = (float*)d_out;
    const int B = in_sizes[0] / 8;  // 65536 rows
    const int grid = (B + ROWS_PER_BLOCK - 1) / ROWS_PER_BLOCK;  // 2048
    hipLaunchKernelGGL(TotalDegree_29755533426739_kernel,
                       dim3(grid), dim3(256), 0, stream, x, out, B);
}